// Round 1
// baseline (7008.324 us; speedup 1.0000x reference)
//
#include <hip/hip_runtime.h>

#define HWSZ (192*192)

// ---------------------------------------------------------------------------
// K1: fused window attention: qkv -> scores+bias -> softmax -> PV -> proj,
// residual add. One block per 8x8 window (4608 blocks).
// ---------------------------------------------------------------------------
__global__ __launch_bounds__(256)
void attn_kernel(const float* __restrict__ x,
                 const float* __restrict__ qkv_w, const float* __restrict__ qkv_b,
                 const float* __restrict__ proj_w, const float* __restrict__ proj_b,
                 const float* __restrict__ bias_tab,
                 float* __restrict__ out)
{
    __shared__ __align__(16) float xs[192][68];   // xs[c][t]
    __shared__ __align__(16) float qs[48][68];    // q[dd][t]
    __shared__ __align__(16) float ks[48][68];    // k[dd][u]
    __shared__ __align__(16) float vs[64][49];    // v[u][dd]
    __shared__ __align__(16) float sc[64][68];    // scores/probs [u][t]
    __shared__ __align__(16) float oh[48][68];    // head out [dd][t]

    const int tid = threadIdx.x;
    const int wid = blockIdx.x;
    const int b   = wid / 576;
    const int wr  = wid - b*576;
    const int wi  = wr / 24;
    const int wj  = wr - wi*24;

    const float* xb = x + (size_t)b*192*HWSZ + (size_t)(wi*8)*192 + wj*8;

    // load window: xs[c][t], t = ty*8+tx
    for (int idx = tid; idx < 192*64; idx += 256) {
        int c = idx >> 6, t = idx & 63;
        xs[c][t] = xb[(size_t)c*HWSZ + (t>>3)*192 + (t&7)];
    }
    __syncthreads();

    const int tg = tid & 15;
    const int t0 = tg*4;
    const int og = tid >> 4;      // 0..15

    float pacc[12][4];
    #pragma unroll
    for (int o=0;o<12;o++){ pacc[o][0]=0.f;pacc[o][1]=0.f;pacc[o][2]=0.f;pacc[o][3]=0.f; }

    const float scale = 0.14433756729740643f; // 1/sqrt(48)

    for (int h=0; h<4; ++h) {
        // ---- qkv: thread computes j = og*9+jj (0..143 -> q/k/v of this head) ----
        {
            int rows[9];
            #pragma unroll
            for (int jj=0;jj<9;jj++){
                int j = og*9+jj;
                rows[jj] = (j<48) ? (h*48+j) : (j<96) ? (192+h*48+j-48) : (384+h*48+j-96);
            }
            float acc[9][4];
            #pragma unroll
            for (int jj=0;jj<9;jj++){acc[jj][0]=0.f;acc[jj][1]=0.f;acc[jj][2]=0.f;acc[jj][3]=0.f;}
            #pragma unroll 4
            for (int c=0;c<192;++c){
                const float4 xv4 = *(const float4*)&xs[c][t0];
                const float xv[4] = {xv4.x, xv4.y, xv4.z, xv4.w};
                #pragma unroll
                for (int jj=0;jj<9;jj++){
                    const float w = qkv_w[rows[jj]*192 + c];
                    #pragma unroll
                    for (int i=0;i<4;i++) acc[jj][i] += xv[i]*w;
                }
            }
            #pragma unroll
            for (int jj=0;jj<9;jj++){
                const int j = og*9+jj;
                const float qb = qkv_b[rows[jj]];
                #pragma unroll
                for (int i=0;i<4;i++){
                    const float v = acc[jj][i] + qb;
                    if (j<48)       qs[j][t0+i]      = v;
                    else if (j<96)  ks[j-48][t0+i]   = v;
                    else            vs[t0+i][j-96]   = v;
                }
            }
        }
        __syncthreads();

        // ---- scores + relative position bias ----
        {
            const int u0 = og*4;
            float s[4][4];
            #pragma unroll
            for (int i=0;i<4;i++){s[i][0]=0.f;s[i][1]=0.f;s[i][2]=0.f;s[i][3]=0.f;}
            #pragma unroll 4
            for (int dd=0; dd<48; ++dd){
                const float4 qv4 = *(const float4*)&qs[dd][t0];
                const float4 kv4 = *(const float4*)&ks[dd][u0];
                const float qv[4] = {qv4.x,qv4.y,qv4.z,qv4.w};
                const float kv[4] = {kv4.x,kv4.y,kv4.z,kv4.w};
                #pragma unroll
                for (int i=0;i<4;i++)
                    #pragma unroll
                    for (int j=0;j<4;j++) s[i][j] += qv[i]*kv[j];
            }
            #pragma unroll
            for (int i=0;i<4;i++){
                const int t=t0+i, ty=t>>3, tx=t&7;
                #pragma unroll
                for (int j=0;j<4;j++){
                    const int u=u0+j, uy=u>>3, ux=u&7;
                    sc[u][t] = s[i][j]*scale + bias_tab[(ty-uy+7)*15 + (tx-ux+7)];
                }
            }
        }
        __syncthreads();

        // ---- softmax over u (keys) per t: 4 threads per row, shfl combine ----
        {
            const int t = tid >> 2;
            const int part = tid & 3;
            float m = -1e30f;
            #pragma unroll
            for (int uu=0; uu<16; ++uu) m = fmaxf(m, sc[part*16+uu][t]);
            m = fmaxf(m, __shfl_xor(m, 1));
            m = fmaxf(m, __shfl_xor(m, 2));
            float l = 0.f;
            float e[16];
            #pragma unroll
            for (int uu=0; uu<16; ++uu){ e[uu] = __expf(sc[part*16+uu][t]-m); l += e[uu]; }
            l += __shfl_xor(l,1);
            l += __shfl_xor(l,2);
            const float inv = 1.f/l;
            #pragma unroll
            for (int uu=0; uu<16; ++uu) sc[part*16+uu][t] = e[uu]*inv;
        }
        __syncthreads();

        // ---- PV: out_h[dd][t] ----
        {
            const int d0 = og*3;
            float o3[3][4];
            #pragma unroll
            for (int jj=0;jj<3;jj++){o3[jj][0]=0.f;o3[jj][1]=0.f;o3[jj][2]=0.f;o3[jj][3]=0.f;}
            #pragma unroll 4
            for (int u=0; u<64; ++u){
                const float4 pv4 = *(const float4*)&sc[u][t0];
                const float pv[4] = {pv4.x,pv4.y,pv4.z,pv4.w};
                #pragma unroll
                for (int jj=0;jj<3;jj++){
                    const float vvv = vs[u][d0+jj];
                    #pragma unroll
                    for (int i=0;i<4;i++) o3[jj][i] += pv[i]*vvv;
                }
            }
            #pragma unroll
            for (int jj=0;jj<3;jj++)
                #pragma unroll
                for (int i=0;i<4;i++) oh[d0+jj][t0+i] = o3[jj][i];
        }
        __syncthreads();

        // ---- proj partial accumulation over this head's 48 channels ----
        {
            const int o0 = og*12;
            #pragma unroll 4
            for (int dd=0; dd<48; ++dd){
                const float4 ov4 = *(const float4*)&oh[dd][t0];
                const float ov[4] = {ov4.x,ov4.y,ov4.z,ov4.w};
                #pragma unroll
                for (int oo=0;oo<12;oo++){
                    const float w = proj_w[(o0+oo)*192 + h*48+dd];
                    #pragma unroll
                    for (int i=0;i<4;i++) pacc[oo][i] += ov[i]*w;
                }
            }
        }
        __syncthreads();   // before next head reuses qs/ks/vs/sc/oh
    }

    // ---- epilogue: out = x + attn + proj_b ----
    {
        const int o0 = og*12;
        float* ob = out + (size_t)b*192*HWSZ + (size_t)(wi*8)*192 + wj*8;
        #pragma unroll
        for (int oo=0;oo<12;oo++){
            const int oc = o0+oo;
            const float pb = proj_b[oc];
            #pragma unroll
            for (int i=0;i<4;i++){
                const int t = t0+i;
                ob[(size_t)oc*HWSZ + (t>>3)*192 + (t&7)] = pacc[oo][i] + pb + xs[oc][t];
            }
        }
    }
}

// ---------------------------------------------------------------------------
// K2: 1x1 conv (C->2C) + GLU.  g = a * sigmoid(b).  64-pixel row tiles.
// ---------------------------------------------------------------------------
__global__ __launch_bounds__(256)
void glu_kernel(const float* __restrict__ x1, const float* __restrict__ w1_w,
                const float* __restrict__ w1_b, float* __restrict__ g)
{
    __shared__ __align__(16) float xs[192][68];
    const int tid = threadIdx.x;
    const int bimg = blockIdx.x / 576;       // 576 = 36864/64 tiles per image
    const int rem  = blockIdx.x - bimg*576;
    const int y    = rem / 3;
    const int x0   = (rem - y*3) * 64;

    const float* xb = x1 + (size_t)bimg*192*HWSZ + (size_t)y*192 + x0;
    for (int idx = tid; idx < 192*64; idx += 256){
        int c = idx >> 6, t = idx & 63;
        xs[c][t] = xb[(size_t)c*HWSZ + t];
    }
    __syncthreads();

    const int p0 = (tid & 15)*4;
    const int og = tid >> 4;
    const int o0 = og*12;

    float accA[12][4], accB[12][4];
    #pragma unroll
    for (int oo=0;oo<12;oo++){
        #pragma unroll
        for (int i=0;i<4;i++){ accA[oo][i]=0.f; accB[oo][i]=0.f; }
    }
    #pragma unroll 2
    for (int c=0;c<192;++c){
        const float4 xv4 = *(const float4*)&xs[c][p0];
        const float xv[4] = {xv4.x,xv4.y,xv4.z,xv4.w};
        #pragma unroll
        for (int oo=0;oo<12;oo++){
            const float wa = w1_w[(o0+oo)*192 + c];
            const float wb = w1_w[(o0+oo+192)*192 + c];
            #pragma unroll
            for (int i=0;i<4;i++){ accA[oo][i] += xv[i]*wa; accB[oo][i] += xv[i]*wb; }
        }
    }

    float* gb = g + (size_t)bimg*192*HWSZ + (size_t)y*192 + x0;
    #pragma unroll
    for (int oo=0;oo<12;oo++){
        const int o = o0+oo;
        const float ba = w1_b[o], bb = w1_b[o+192];
        #pragma unroll
        for (int i=0;i<4;i++){
            const float a = accA[oo][i] + ba;
            const float bv = accB[oo][i] + bb;
            gb[(size_t)o*HWSZ + p0 + i] = a * (1.f/(1.f+__expf(-bv)));
        }
    }
}

// ---------------------------------------------------------------------------
// K3: 3x3 conv (replication pad via clamp) + bias + leaky_relu(0.2) + residual.
// Tile: 16x16 pixels x 32 out channels; KC=16 input-channel chunks in LDS.
// In-place update of d_out (each address owned by exactly one thread).
// ---------------------------------------------------------------------------
#define KC 16
__global__ __launch_bounds__(256)
void conv_kernel(const float* __restrict__ g, const float* __restrict__ w2_w,
                 const float* __restrict__ w2_b, float* __restrict__ out)
{
    __shared__ __align__(16) float gt[KC][18][18];
    __shared__ __align__(16) float wt[KC][9][33];

    int bid = blockIdx.x;
    const int tX = bid % 12; bid /= 12;
    const int tY = bid % 12; bid /= 12;
    const int ob = bid % 6;  bid /= 6;
    const int bimg = bid;                 // 0..7
    const int tx0 = tX*16, ty0 = tY*16, oc0 = ob*32;

    const int tid = threadIdx.x;
    const int pg  = tid & 63;
    const int ocg = tid >> 6;             // wave-uniform 0..3
    const int lx0 = (pg & 3)*4;
    const int ly  = pg >> 2;              // 0..15
    const int o0  = ocg*8;

    float acc[8][4];
    #pragma unroll
    for (int o=0;o<8;o++){acc[o][0]=0.f;acc[o][1]=0.f;acc[o][2]=0.f;acc[o][3]=0.f;}

    for (int c0=0; c0<192; c0+=KC){
        // g tile with replication-pad clamp
        for (int idx = tid; idx < KC*18*18; idx += 256){
            int c = idx / 324; int r2 = idx - c*324; int iy = r2/18, ix = r2 - iy*18;
            int gy = ty0 + iy - 1; gy = min(max(gy,0),191);
            int gx = tx0 + ix - 1; gx = min(max(gx,0),191);
            gt[c][iy][ix] = g[((size_t)(bimg*192 + c0 + c))*HWSZ + (size_t)gy*192 + gx];
        }
        // weight tile: wt[c][k][o]
        for (int idx = tid; idx < KC*9*32; idx += 256){
            int o = idx / 144; int r2 = idx - o*144; int c = r2/9, k = r2 - c*9;
            wt[c][k][o] = w2_w[((size_t)(oc0+o)*192 + (c0+c))*9 + k];
        }
        __syncthreads();

        for (int c=0; c<KC; ++c){
            #pragma unroll
            for (int ky=0; ky<3; ++ky){
                float gb6[6];
                #pragma unroll
                for (int i=0;i<6;i++) gb6[i] = gt[c][ly+ky][lx0+i];
                #pragma unroll
                for (int kx=0; kx<3; ++kx){
                    #pragma unroll
                    for (int o=0;o<8;o++){
                        const float w = wt[c][ky*3+kx][o0+o];
                        acc[o][0] += gb6[kx+0]*w;
                        acc[o][1] += gb6[kx+1]*w;
                        acc[o][2] += gb6[kx+2]*w;
                        acc[o][3] += gb6[kx+3]*w;
                    }
                }
            }
        }
        __syncthreads();
    }

    // epilogue: out = x1 + leaky(conv + bias)
    #pragma unroll
    for (int o=0;o<8;o++){
        const int oc = oc0 + o0 + o;
        const float bias = w2_b[oc];
        const size_t base = ((size_t)(bimg*192+oc))*HWSZ + (size_t)(ty0+ly)*192 + tx0+lx0;
        float4 xv = *(const float4*)&out[base];
        float4 r;
        float y0 = acc[o][0]+bias; y0 = (y0>=0.f)?y0:0.2f*y0;
        float y1 = acc[o][1]+bias; y1 = (y1>=0.f)?y1:0.2f*y1;
        float y2 = acc[o][2]+bias; y2 = (y2>=0.f)?y2:0.2f*y2;
        float y3 = acc[o][3]+bias; y3 = (y3>=0.f)?y3:0.2f*y3;
        r.x = xv.x + y0; r.y = xv.y + y1; r.z = xv.z + y2; r.w = xv.w + y3;
        *(float4*)&out[base] = r;
    }
}

// ---------------------------------------------------------------------------
extern "C" void kernel_launch(void* const* d_in, const int* in_sizes, int n_in,
                              void* d_out, int out_size, void* d_ws, size_t ws_size,
                              hipStream_t stream)
{
    const float* x        = (const float*)d_in[0];
    const float* qkv_w    = (const float*)d_in[1];
    const float* qkv_b    = (const float*)d_in[2];
    const float* proj_w   = (const float*)d_in[3];
    const float* proj_b   = (const float*)d_in[4];
    const float* bias_tab = (const float*)d_in[5];
    const float* w1_w     = (const float*)d_in[6];
    const float* w1_b     = (const float*)d_in[7];
    const float* w2_w     = (const float*)d_in[8];
    const float* w2_b     = (const float*)d_in[9];
    float* out = (float*)d_out;
    float* g   = (float*)d_ws;   // 8*192*192*192 floats = 226.5 MB

    attn_kernel<<<4608, 256, 0, stream>>>(x, qkv_w, qkv_b, proj_w, proj_b, bias_tab, out);
    glu_kernel <<<4608, 256, 0, stream>>>(out, w1_w, w1_b, g);
    conv_kernel<<<6912, 256, 0, stream>>>(g, w2_w, w2_b, out);
}

// Round 2
// 4321.746 us; speedup vs baseline: 1.6216x; 1.6216x over previous
//
#include <hip/hip_runtime.h>
#include <hip/hip_bf16.h>

#define HWSZ (192*192)

typedef __attribute__((ext_vector_type(8))) short short8v;
typedef __attribute__((ext_vector_type(4))) float f32x4;

// ---------------------------------------------------------------------------
// K1: fused window attention: qkv -> scores+bias -> softmax -> PV -> proj,
// residual add. One block per 8x8 window (4608 blocks). (unchanged from R1)
// ---------------------------------------------------------------------------
__global__ __launch_bounds__(256)
void attn_kernel(const float* __restrict__ x,
                 const float* __restrict__ qkv_w, const float* __restrict__ qkv_b,
                 const float* __restrict__ proj_w, const float* __restrict__ proj_b,
                 const float* __restrict__ bias_tab,
                 float* __restrict__ out)
{
    __shared__ __align__(16) float xs[192][68];   // xs[c][t]
    __shared__ __align__(16) float qs[48][68];    // q[dd][t]
    __shared__ __align__(16) float ks[48][68];    // k[dd][u]
    __shared__ __align__(16) float vs[64][49];    // v[u][dd]
    __shared__ __align__(16) float sc[64][68];    // scores/probs [u][t]
    __shared__ __align__(16) float oh[48][68];    // head out [dd][t]

    const int tid = threadIdx.x;
    const int wid = blockIdx.x;
    const int b   = wid / 576;
    const int wr  = wid - b*576;
    const int wi  = wr / 24;
    const int wj  = wr - wi*24;

    const float* xb = x + (size_t)b*192*HWSZ + (size_t)(wi*8)*192 + wj*8;

    for (int idx = tid; idx < 192*64; idx += 256) {
        int c = idx >> 6, t = idx & 63;
        xs[c][t] = xb[(size_t)c*HWSZ + (t>>3)*192 + (t&7)];
    }
    __syncthreads();

    const int tg = tid & 15;
    const int t0 = tg*4;
    const int og = tid >> 4;      // 0..15

    float pacc[12][4];
    #pragma unroll
    for (int o=0;o<12;o++){ pacc[o][0]=0.f;pacc[o][1]=0.f;pacc[o][2]=0.f;pacc[o][3]=0.f; }

    const float scale = 0.14433756729740643f; // 1/sqrt(48)

    for (int h=0; h<4; ++h) {
        {
            int rows[9];
            #pragma unroll
            for (int jj=0;jj<9;jj++){
                int j = og*9+jj;
                rows[jj] = (j<48) ? (h*48+j) : (j<96) ? (192+h*48+j-48) : (384+h*48+j-96);
            }
            float acc[9][4];
            #pragma unroll
            for (int jj=0;jj<9;jj++){acc[jj][0]=0.f;acc[jj][1]=0.f;acc[jj][2]=0.f;acc[jj][3]=0.f;}
            #pragma unroll 4
            for (int c=0;c<192;++c){
                const float4 xv4 = *(const float4*)&xs[c][t0];
                const float xv[4] = {xv4.x, xv4.y, xv4.z, xv4.w};
                #pragma unroll
                for (int jj=0;jj<9;jj++){
                    const float w = qkv_w[rows[jj]*192 + c];
                    #pragma unroll
                    for (int i=0;i<4;i++) acc[jj][i] += xv[i]*w;
                }
            }
            #pragma unroll
            for (int jj=0;jj<9;jj++){
                const int j = og*9+jj;
                const float qb = qkv_b[rows[jj]];
                #pragma unroll
                for (int i=0;i<4;i++){
                    const float v = acc[jj][i] + qb;
                    if (j<48)       qs[j][t0+i]      = v;
                    else if (j<96)  ks[j-48][t0+i]   = v;
                    else            vs[t0+i][j-96]   = v;
                }
            }
        }
        __syncthreads();

        {
            const int u0 = og*4;
            float s[4][4];
            #pragma unroll
            for (int i=0;i<4;i++){s[i][0]=0.f;s[i][1]=0.f;s[i][2]=0.f;s[i][3]=0.f;}
            #pragma unroll 4
            for (int dd=0; dd<48; ++dd){
                const float4 qv4 = *(const float4*)&qs[dd][t0];
                const float4 kv4 = *(const float4*)&ks[dd][u0];
                const float qv[4] = {qv4.x,qv4.y,qv4.z,qv4.w};
                const float kv[4] = {kv4.x,kv4.y,kv4.z,kv4.w};
                #pragma unroll
                for (int i=0;i<4;i++)
                    #pragma unroll
                    for (int j=0;j<4;j++) s[i][j] += qv[i]*kv[j];
            }
            #pragma unroll
            for (int i=0;i<4;i++){
                const int t=t0+i, ty=t>>3, tx=t&7;
                #pragma unroll
                for (int j=0;j<4;j++){
                    const int u=u0+j, uy=u>>3, ux=u&7;
                    sc[u][t] = s[i][j]*scale + bias_tab[(ty-uy+7)*15 + (tx-ux+7)];
                }
            }
        }
        __syncthreads();

        {
            const int t = tid >> 2;
            const int part = tid & 3;
            float m = -1e30f;
            #pragma unroll
            for (int uu=0; uu<16; ++uu) m = fmaxf(m, sc[part*16+uu][t]);
            m = fmaxf(m, __shfl_xor(m, 1));
            m = fmaxf(m, __shfl_xor(m, 2));
            float l = 0.f;
            float e[16];
            #pragma unroll
            for (int uu=0; uu<16; ++uu){ e[uu] = __expf(sc[part*16+uu][t]-m); l += e[uu]; }
            l += __shfl_xor(l,1);
            l += __shfl_xor(l,2);
            const float inv = 1.f/l;
            #pragma unroll
            for (int uu=0; uu<16; ++uu) sc[part*16+uu][t] = e[uu]*inv;
        }
        __syncthreads();

        {
            const int d0 = og*3;
            float o3[3][4];
            #pragma unroll
            for (int jj=0;jj<3;jj++){o3[jj][0]=0.f;o3[jj][1]=0.f;o3[jj][2]=0.f;o3[jj][3]=0.f;}
            #pragma unroll 4
            for (int u=0; u<64; ++u){
                const float4 pv4 = *(const float4*)&sc[u][t0];
                const float pv[4] = {pv4.x,pv4.y,pv4.z,pv4.w};
                #pragma unroll
                for (int jj=0;jj<3;jj++){
                    const float vvv = vs[u][d0+jj];
                    #pragma unroll
                    for (int i=0;i<4;i++) o3[jj][i] += pv[i]*vvv;
                }
            }
            #pragma unroll
            for (int jj=0;jj<3;jj++)
                #pragma unroll
                for (int i=0;i<4;i++) oh[d0+jj][t0+i] = o3[jj][i];
        }
        __syncthreads();

        {
            const int o0 = og*12;
            #pragma unroll 4
            for (int dd=0; dd<48; ++dd){
                const float4 ov4 = *(const float4*)&oh[dd][t0];
                const float ov[4] = {ov4.x,ov4.y,ov4.z,ov4.w};
                #pragma unroll
                for (int oo=0;oo<12;oo++){
                    const float w = proj_w[(o0+oo)*192 + h*48+dd];
                    #pragma unroll
                    for (int i=0;i<4;i++) pacc[oo][i] += ov[i]*w;
                }
            }
        }
        __syncthreads();
    }

    {
        const int o0 = og*12;
        float* ob = out + (size_t)b*192*HWSZ + (size_t)(wi*8)*192 + wj*8;
        #pragma unroll
        for (int oo=0;oo<12;oo++){
            const int oc = o0+oo;
            const float pb = proj_b[oc];
            #pragma unroll
            for (int i=0;i<4;i++){
                const int t = t0+i;
                ob[(size_t)oc*HWSZ + (t>>3)*192 + (t&7)] = pacc[oo][i] + pb + xs[oc][t];
            }
        }
    }
}

// ---------------------------------------------------------------------------
// K2: 1x1 conv (C->2C) + GLU. Writes g as bf16 in PIXEL-MAJOR layout:
// g[img][y][x][c] (c innermost). LDS transpose for coalesced stores.
// ---------------------------------------------------------------------------
__global__ __launch_bounds__(256)
void glu_kernel(const float* __restrict__ x1, const float* __restrict__ w1_w,
                const float* __restrict__ w1_b, __hip_bfloat16* __restrict__ g)
{
    __shared__ __align__(16) float xs[192][68];
    __shared__ __align__(16) __hip_bfloat16 sg[64][200];  // [pixel][oc]

    const int tid = threadIdx.x;
    const int bimg = blockIdx.x / 576;
    const int rem  = blockIdx.x - bimg*576;
    const int y    = rem / 3;
    const int x0   = (rem - y*3) * 64;

    const float* xb = x1 + (size_t)bimg*192*HWSZ + (size_t)y*192 + x0;
    for (int idx = tid; idx < 192*64; idx += 256){
        int c = idx >> 6, t = idx & 63;
        xs[c][t] = xb[(size_t)c*HWSZ + t];
    }
    __syncthreads();

    const int p0 = (tid & 15)*4;
    const int og = tid >> 4;
    const int o0 = og*12;

    float accA[12][4], accB[12][4];
    #pragma unroll
    for (int oo=0;oo<12;oo++){
        #pragma unroll
        for (int i=0;i<4;i++){ accA[oo][i]=0.f; accB[oo][i]=0.f; }
    }
    #pragma unroll 2
    for (int c=0;c<192;++c){
        const float4 xv4 = *(const float4*)&xs[c][p0];
        const float xv[4] = {xv4.x,xv4.y,xv4.z,xv4.w};
        #pragma unroll
        for (int oo=0;oo<12;oo++){
            const float wa = w1_w[(o0+oo)*192 + c];
            const float wb = w1_w[(o0+oo+192)*192 + c];
            #pragma unroll
            for (int i=0;i<4;i++){ accA[oo][i] += xv[i]*wa; accB[oo][i] += xv[i]*wb; }
        }
    }

    #pragma unroll
    for (int oo=0;oo<12;oo++){
        const int o = o0+oo;
        const float ba = w1_b[o], bb = w1_b[o+192];
        #pragma unroll
        for (int i=0;i<4;i++){
            const float a = accA[oo][i] + ba;
            const float bv = accB[oo][i] + bb;
            sg[p0+i][o] = __float2bfloat16(a * (1.f/(1.f+__expf(-bv))));
        }
    }
    __syncthreads();

    // coalesced store: 64 pixels x 192 channels bf16, contiguous 24 KB
    __hip_bfloat16* gb = g + ((size_t)bimg*HWSZ + (size_t)y*192 + x0)*192;
    for (int idx = tid; idx < 1536; idx += 256){
        int p = idx / 24;
        int j0 = (idx - p*24)*8;
        *(uint4*)&gb[(size_t)p*192 + j0] = *(const uint4*)&sg[p][j0];
    }
}

// ---------------------------------------------------------------------------
// K-prep: transpose conv weights to [tap][oc][c] bf16 in ws
// ---------------------------------------------------------------------------
__global__ __launch_bounds__(256)
void prep_w(const float* __restrict__ w2_w, __hip_bfloat16* __restrict__ wg)
{
    int i = blockIdx.x*256 + threadIdx.x;
    if (i >= 9*192*192) return;
    int tap = i / 36864; int r = i - tap*36864;
    int oc = r / 192;    int c = r - oc*192;
    wg[i] = __float2bfloat16(w2_w[((size_t)oc*192 + c)*9 + tap]);
}

// ---------------------------------------------------------------------------
// K3: 3x3 conv via 9-tap shifted MFMA GEMM (bf16 in, fp32 acc).
// Block: 96 oc x (16x8) pixels. 4 waves 2x2: wave = 48 oc x (16x4) px
//  = 3x4 tiles of mfma_f32_16x16x32_bf16. K = 32-ch chunks x 9 taps.
// B-frag: lane&15 = pixel x, (lane>>4)*8 = k-offset -> 16B aligned ds_read
// for ANY tap shift (shift moves the LDS row, not the alignment).
// ---------------------------------------------------------------------------
#define KC 32
__global__ __launch_bounds__(256)
void conv_mfma(const __hip_bfloat16* __restrict__ g,
               const __hip_bfloat16* __restrict__ wg,
               const float* __restrict__ w2_b, float* __restrict__ out)
{
    __shared__ __align__(16) __hip_bfloat16 gt[10*18*32];  // [y'][x'][c]
    __shared__ __align__(16) __hip_bfloat16 wt[9*96*32];   // [tap][oc_l][c]

    int bid = blockIdx.x;
    const int tX = bid % 12; bid /= 12;
    const int tY = bid % 24; bid /= 24;
    const int ob = bid & 1;  bid >>= 1;
    const int bimg = bid;
    const int tx0 = tX*16, ty0 = tY*8, oc0 = ob*96;

    const int tid  = threadIdx.x;
    const int lane = tid & 63;
    const int wv   = tid >> 6;
    const int wm   = wv >> 1;      // oc half (48)
    const int wn   = wv & 1;       // row half (4 rows)
    const int lx   = lane & 15;
    const int kg   = lane >> 4;    // k-group 0..3

    f32x4 acc[3][4];
    #pragma unroll
    for (int m=0;m<3;m++)
        #pragma unroll
        for (int n=0;n<4;n++) acc[m][n] = (f32x4){0.f,0.f,0.f,0.f};

    const size_t gbase = (size_t)bimg*HWSZ;

    for (int c0 = 0; c0 < 192; c0 += KC) {
        // stage g tile (18x10 halo, replication clamp), 32 channels
        for (int idx = tid; idx < 720; idx += 256) {
            int px = idx >> 2, part = idx & 3;
            int iy = px / 18, ix = px - iy*18;
            int gy = min(max(ty0 + iy - 1, 0), 191);
            int gx = min(max(tx0 + ix - 1, 0), 191);
            *(uint4*)&gt[(iy*18+ix)*32 + part*8] =
                *(const uint4*)&g[(gbase + (size_t)gy*192 + gx)*192 + c0 + part*8];
        }
        // stage weights: 9 taps x 96 oc x 32 c
        for (int idx = tid; idx < 3456; idx += 256) {
            int tap = idx / 384; int rr = idx - tap*384;
            int ocl = rr >> 2, part = rr & 3;
            *(uint4*)&wt[(tap*96+ocl)*32 + part*8] =
                *(const uint4*)&wg[(size_t)tap*36864 + (size_t)(oc0+ocl)*192 + c0 + part*8];
        }
        __syncthreads();

        #pragma unroll
        for (int ky=0; ky<3; ++ky) {
            #pragma unroll
            for (int kx=0; kx<3; ++kx) {
                const int tap = ky*3+kx;
                short8v a[3], b[4];
                #pragma unroll
                for (int m=0;m<3;m++)
                    a[m] = *(const short8v*)&wt[(tap*96 + wm*48 + m*16 + lx)*32 + kg*8];
                #pragma unroll
                for (int n=0;n<4;n++)
                    b[n] = *(const short8v*)&gt[((wn*4 + n + ky)*18 + lx + kx)*32 + kg*8];
                #pragma unroll
                for (int m=0;m<3;m++)
                    #pragma unroll
                    for (int n=0;n<4;n++)
                        acc[m][n] = __builtin_amdgcn_mfma_f32_16x16x32_bf16(
                                        a[m], b[n], acc[m][n], 0, 0, 0);
            }
        }
        __syncthreads();
    }

    // epilogue: out += leaky(conv + bias)   (C/D: col=lane&15=x, row=(lane>>4)*4+r=oc)
    #pragma unroll
    for (int m=0;m<3;m++) {
        const int ocb_ = oc0 + wm*48 + m*16 + kg*4;
        #pragma unroll
        for (int n=0;n<4;n++) {
            const int y = ty0 + wn*4 + n;
            const int x = tx0 + lx;
            #pragma unroll
            for (int r=0;r<4;r++) {
                const int oc = ocb_ + r;
                const size_t o = ((size_t)(bimg*192+oc))*HWSZ + (size_t)y*192 + x;
                float v = acc[m][n][r] + w2_b[oc];
                v = (v >= 0.f) ? v : 0.2f*v;
                out[o] += v;
            }
        }
    }
}

// ---------------------------------------------------------------------------
extern "C" void kernel_launch(void* const* d_in, const int* in_sizes, int n_in,
                              void* d_out, int out_size, void* d_ws, size_t ws_size,
                              hipStream_t stream)
{
    const float* x        = (const float*)d_in[0];
    const float* qkv_w    = (const float*)d_in[1];
    const float* qkv_b    = (const float*)d_in[2];
    const float* proj_w   = (const float*)d_in[3];
    const float* proj_b   = (const float*)d_in[4];
    const float* bias_tab = (const float*)d_in[5];
    const float* w1_w     = (const float*)d_in[6];
    const float* w1_b     = (const float*)d_in[7];
    const float* w2_w     = (const float*)d_in[8];
    const float* w2_b     = (const float*)d_in[9];
    float* out = (float*)d_out;

    __hip_bfloat16* g  = (__hip_bfloat16*)d_ws;                      // 113.2 MB
    __hip_bfloat16* wg = (__hip_bfloat16*)((char*)d_ws + (size_t)8*HWSZ*192*2);

    prep_w<<<1296, 256, 0, stream>>>(w2_w, wg);
    attn_kernel<<<4608, 256, 0, stream>>>(x, qkv_w, qkv_b, proj_w, proj_b, bias_tab, out);
    glu_kernel <<<4608, 256, 0, stream>>>(out, w1_w, w1_b, g);
    conv_mfma  <<<4608, 256, 0, stream>>>(g, wg, w2_b, out);
}

// Round 3
// 1133.157 us; speedup vs baseline: 6.1848x; 3.8139x over previous
//
#include <hip/hip_runtime.h>
#include <hip/hip_bf16.h>

#define HWSZ (192*192)

typedef __attribute__((ext_vector_type(8))) short short8v;
typedef __attribute__((ext_vector_type(4))) float f32x4;

// ws element counts for prep'd weights
#define WG_N 331776   // conv w: [tap][oc][c]           9*192*192
#define WQ_N 110592   // qkv  w: [h][144][192]          4*144*192
#define PW_N 49152    // proj w: [h][192][64] (d pad 64) 4*192*64
#define W1_N 73728    // glu  w: [384][192] straight cast

// ---------------------------------------------------------------------------
// prep: cast/reorder all weights to bf16 layouts used by the MFMA kernels
// ---------------------------------------------------------------------------
__global__ __launch_bounds__(256)
void prep_weights(const float* __restrict__ w2_w, const float* __restrict__ qkv_w,
                  const float* __restrict__ proj_w, const float* __restrict__ w1_w,
                  __hip_bfloat16* __restrict__ wg, __hip_bfloat16* __restrict__ wq,
                  __hip_bfloat16* __restrict__ pw, __hip_bfloat16* __restrict__ w1b)
{
    int i = blockIdx.x*256 + threadIdx.x;
    if (i < WG_N) {
        int tap = i / 36864; int r = i - tap*36864;
        int oc = r / 192;    int c = r - oc*192;
        wg[i] = __float2bfloat16(w2_w[((size_t)oc*192 + c)*9 + tap]);
    } else if (i < WG_N + WQ_N) {
        int j2 = i - WG_N;
        int h = j2 / 27648; int r = j2 - h*27648;
        int j = r / 192;    int c = r - j*192;
        int row = (j<48) ? h*48+j : (j<96) ? 192+h*48+(j-48) : 384+h*48+(j-96);
        wq[j2] = __float2bfloat16(qkv_w[(size_t)row*192 + c]);
    } else if (i < WG_N + WQ_N + PW_N) {
        int j2 = i - WG_N - WQ_N;
        int h = j2 / 12288; int r = j2 - h*12288;
        int oc = r / 64;    int dd = r - oc*64;
        pw[j2] = (dd < 48) ? __float2bfloat16(proj_w[(size_t)oc*192 + h*48 + dd])
                           : __float2bfloat16(0.f);
    } else if (i < WG_N + WQ_N + PW_N + W1_N) {
        int j2 = i - WG_N - WQ_N - PW_N;
        w1b[j2] = __float2bfloat16(w1_w[j2]);
    }
}

// ---------------------------------------------------------------------------
// K1: fused window attention, full MFMA. 1 block = 1 window (64 tokens).
// 4 waves. Fragment convention (HW-verified in R2 conv):
//   A/B-frag: lane&15 = non-K index, k = (lane>>4)*8 + 0..7 contiguous in mem
//   D: row = (lane>>4)*4 + r, col = lane&15
// ---------------------------------------------------------------------------
__global__ __launch_bounds__(256)
void attn_mfma(const float* __restrict__ x,
               const __hip_bfloat16* __restrict__ wq,
               const float* __restrict__ qkv_b,
               const __hip_bfloat16* __restrict__ pw,
               const float* __restrict__ proj_b,
               const float* __restrict__ bias_tab,
               float* __restrict__ out)
{
    __shared__ __align__(16) __hip_bfloat16 Xs[64][200];   // [t][c]
    __shared__ __align__(16) __hip_bfloat16 q_lds[64][72]; // [t][d pad64]
    __shared__ __align__(16) __hip_bfloat16 k_lds[64][72]; // [t][d pad64]
    __shared__ __align__(16) __hip_bfloat16 v_lds[48][72]; // [d][t]
    __shared__ __align__(16) __hip_bfloat16 p_lds[64][72]; // [tq][tk]
    __shared__ __align__(16) __hip_bfloat16 o_lds[64][72]; // [tq][d pad64]
    __shared__ float tabs[225];

    const int tid = threadIdx.x;
    const int wid = blockIdx.x;
    const int b   = wid / 576;
    const int wr  = wid - b*576;
    const int wi  = wr / 24;
    const int wj  = wr - wi*24;

    const float* xb = x + (size_t)b*192*HWSZ + (size_t)(wi*8)*192 + wj*8;

    for (int idx = tid; idx < 192*64; idx += 256) {
        int c = idx >> 6, t = idx & 63;
        Xs[t][c] = __float2bfloat16(xb[(size_t)c*HWSZ + (t>>3)*192 + (t&7)]);
    }
    if (tid < 225) tabs[tid] = bias_tab[tid];
    {
        const __hip_bfloat16 z = __float2bfloat16(0.f);
        for (int idx = tid; idx < 1024; idx += 256) {
            int t = idx >> 4, dd = 48 + (idx & 15);
            q_lds[t][dd] = z; k_lds[t][dd] = z; o_lds[t][dd] = z;
        }
    }
    __syncthreads();

    const int lane = tid & 63;
    const int wv   = tid >> 6;
    const int lx   = lane & 15;
    const int kg   = lane >> 4;

    // QKV phase: wave -> disjoint m-tiles [3,2,2,2] of the 9 (j=144) tiles
    const int ms = (wv == 0) ? 0 : 2*wv + 1;
    const int mc = (wv == 0) ? 3 : 2;

    f32x4 pacc[3][4];
    #pragma unroll
    for (int m=0;m<3;m++)
        #pragma unroll
        for (int n=0;n<4;n++) pacc[m][n] = (f32x4){0.f,0.f,0.f,0.f};

    const float scale = 0.14433756729740643f; // 1/sqrt(48)

    #pragma unroll 1
    for (int h=0; h<4; ++h) {
        // ---------- QKV: D[j][t], A=wq[h][j][c], B=Xs[t][c] ----------
        f32x4 qacc[3][4];
        #pragma unroll
        for (int m=0;m<3;m++)
            #pragma unroll
            for (int n=0;n<4;n++) qacc[m][n] = (f32x4){0.f,0.f,0.f,0.f};

        #pragma unroll 1
        for (int kc=0; kc<6; ++kc) {
            short8v bf[4];
            #pragma unroll
            for (int n=0;n<4;n++)
                bf[n] = *(const short8v*)&Xs[n*16+lx][kc*32+kg*8];
            #pragma unroll
            for (int mm=0; mm<3; ++mm) {
                if (mm < mc) {
                    short8v af = *(const short8v*)
                        &wq[(size_t)(h*144 + (ms+mm)*16 + lx)*192 + kc*32 + kg*8];
                    #pragma unroll
                    for (int n=0;n<4;n++)
                        qacc[mm][n] = __builtin_amdgcn_mfma_f32_16x16x32_bf16(
                                          af, bf[n], qacc[mm][n], 0,0,0);
                }
            }
        }
        #pragma unroll
        for (int mm=0; mm<3; ++mm) {
            if (mm < mc) {
                const int j0 = (ms+mm)*16 + kg*4;
                float bias4[4];
                #pragma unroll
                for (int r=0;r<4;r++){
                    int j = j0 + r;
                    int row = (j<48) ? h*48+j : (j<96) ? 192+h*48+(j-48)
                                             : 384+h*48+(j-96);
                    bias4[r] = qkv_b[row];
                }
                #pragma unroll
                for (int n=0;n<4;n++){
                    const int t = n*16 + lx;
                    union { ushort4 u; __hip_bfloat16 e[4]; } pk;
                    #pragma unroll
                    for (int r=0;r<4;r++)
                        pk.e[r] = __float2bfloat16(qacc[mm][n][r] + bias4[r]);
                    if (j0 < 48)      *(ushort4*)&q_lds[t][j0]    = pk.u;
                    else if (j0 < 96) *(ushort4*)&k_lds[t][j0-48] = pk.u;
                    else {
                        #pragma unroll
                        for (int r=0;r<4;r++) v_lds[j0-96+r][t] = pk.e[r];
                    }
                }
            }
        }
        __syncthreads();

        // ---------- scores: D[tq][tk], A=q_lds, B=k_lds, K=64 (padded) ----
        f32x4 sacc[4];
        #pragma unroll
        for (int n=0;n<4;n++) sacc[n] = (f32x4){0.f,0.f,0.f,0.f};
        #pragma unroll
        for (int kc=0; kc<2; ++kc) {
            short8v af = *(const short8v*)&q_lds[wv*16+lx][kc*32+kg*8];
            #pragma unroll
            for (int n=0;n<4;n++) {
                short8v bf = *(const short8v*)&k_lds[n*16+lx][kc*32+kg*8];
                sacc[n] = __builtin_amdgcn_mfma_f32_16x16x32_bf16(af, bf, sacc[n],0,0,0);
            }
        }
        // in-register softmax per row (row lives in 16 lanes of this wave)
        const int tq = wv*16 + kg*4;
        #pragma unroll
        for (int r=0;r<4;r++){
            const int trow = tq + r;
            const int tyq = trow >> 3, txq = trow & 7;
            float s[4];
            float mx = -1e30f;
            #pragma unroll
            for (int n=0;n<4;n++){
                const int tk = n*16 + lx;
                s[n] = sacc[n][r]*scale + tabs[(tyq-(tk>>3)+7)*15 + (txq-(tk&7)+7)];
                mx = fmaxf(mx, s[n]);
            }
            mx = fmaxf(mx, __shfl_xor(mx,1));
            mx = fmaxf(mx, __shfl_xor(mx,2));
            mx = fmaxf(mx, __shfl_xor(mx,4));
            mx = fmaxf(mx, __shfl_xor(mx,8));
            float l = 0.f;
            #pragma unroll
            for (int n=0;n<4;n++){ s[n] = __expf(s[n]-mx); l += s[n]; }
            l += __shfl_xor(l,1); l += __shfl_xor(l,2);
            l += __shfl_xor(l,4); l += __shfl_xor(l,8);
            const float inv = 1.f/l;
            #pragma unroll
            for (int n=0;n<4;n++)
                p_lds[trow][n*16+lx] = __float2bfloat16(s[n]*inv);
        }
        __syncthreads();

        // ---------- PV: D[tq][d], A=p_lds, B=v_lds, K=64 ----------
        f32x4 oacc[3];
        #pragma unroll
        for (int n=0;n<3;n++) oacc[n] = (f32x4){0.f,0.f,0.f,0.f};
        #pragma unroll
        for (int kc=0; kc<2; ++kc) {
            short8v af = *(const short8v*)&p_lds[wv*16+lx][kc*32+kg*8];
            #pragma unroll
            for (int n=0;n<3;n++) {
                short8v bf = *(const short8v*)&v_lds[n*16+lx][kc*32+kg*8];
                oacc[n] = __builtin_amdgcn_mfma_f32_16x16x32_bf16(af, bf, oacc[n],0,0,0);
            }
        }
        #pragma unroll
        for (int n=0;n<3;n++)
            #pragma unroll
            for (int r=0;r<4;r++)
                o_lds[tq+r][n*16+lx] = __float2bfloat16(oacc[n][r]);
        __syncthreads();

        // ---------- proj partial: D[oc][t], A=pw[h][oc][d64], B=o_lds ------
        #pragma unroll
        for (int kc=0; kc<2; ++kc) {
            short8v bf[4];
            #pragma unroll
            for (int n=0;n<4;n++)
                bf[n] = *(const short8v*)&o_lds[n*16+lx][kc*32+kg*8];
            #pragma unroll
            for (int mm=0; mm<3; ++mm) {
                short8v af = *(const short8v*)
                    &pw[(size_t)(h*192 + (wv*3+mm)*16 + lx)*64 + kc*32 + kg*8];
                #pragma unroll
                for (int n=0;n<4;n++)
                    pacc[mm][n] = __builtin_amdgcn_mfma_f32_16x16x32_bf16(
                                      af, bf[n], pacc[mm][n], 0,0,0);
            }
        }
        __syncthreads();   // q/k/v/p/o reused next head
    }

    // ---------- epilogue: out = x + attn + proj_b ----------
    float* og = out + (size_t)b*192*HWSZ + (size_t)(wi*8)*192 + wj*8;
    #pragma unroll
    for (int mm=0; mm<3; ++mm) {
        #pragma unroll
        for (int r=0;r<4;r++) {
            const int oc = (wv*3+mm)*16 + kg*4 + r;
            const float pb = proj_b[oc];
            #pragma unroll
            for (int n=0;n<4;n++) {
                const int t = n*16 + lx;
                const size_t off = (size_t)oc*HWSZ + (t>>3)*192 + (t&7);
                og[off] = xb[off] + pacc[mm][n][r] + pb;
            }
        }
    }
}

// ---------------------------------------------------------------------------
// K2: 1x1 conv (C->2C) + GLU via MFMA. 64-px row tile, M=384, K=192.
// Wave w owns tile pairs (3w+mm, 12+3w+mm) so GLU (a,b) pair is lane-local.
// Writes g bf16 pixel-major [img][y][x][c] (reuses Xs as transpose buffer).
// ---------------------------------------------------------------------------
__global__ __launch_bounds__(256)
void glu_mfma(const float* __restrict__ x1, const __hip_bfloat16* __restrict__ w1b,
              const float* __restrict__ w1_b, __hip_bfloat16* __restrict__ g)
{
    __shared__ __align__(16) __hip_bfloat16 Xs[64][200];   // [t][c] then [t][oc]

    const int tid  = threadIdx.x;
    const int bimg = blockIdx.x / 576;
    const int rem  = blockIdx.x - bimg*576;
    const int y    = rem / 3;
    const int x0   = (rem - y*3) * 64;

    const float* xb = x1 + (size_t)bimg*192*HWSZ + (size_t)y*192 + x0;
    for (int idx = tid; idx < 192*64; idx += 256){
        int c = idx >> 6, t = idx & 63;
        Xs[t][c] = __float2bfloat16(xb[(size_t)c*HWSZ + t]);
    }
    __syncthreads();

    const int lane = tid & 63;
    const int wv   = tid >> 6;
    const int lx   = lane & 15;
    const int kg   = lane >> 4;

    f32x4 gacc[6][4];
    #pragma unroll
    for (int m=0;m<6;m++)
        #pragma unroll
        for (int n=0;n<4;n++) gacc[m][n] = (f32x4){0.f,0.f,0.f,0.f};

    #pragma unroll 1
    for (int kc=0; kc<6; ++kc) {
        short8v bf[4];
        #pragma unroll
        for (int n=0;n<4;n++)
            bf[n] = *(const short8v*)&Xs[n*16+lx][kc*32+kg*8];
        #pragma unroll
        for (int mm=0; mm<6; ++mm) {
            const int m = (mm<3) ? (3*wv+mm) : (12 + 3*wv + mm-3);
            short8v af = *(const short8v*)&w1b[(size_t)(m*16+lx)*192 + kc*32 + kg*8];
            #pragma unroll
            for (int n=0;n<4;n++)
                gacc[mm][n] = __builtin_amdgcn_mfma_f32_16x16x32_bf16(
                                  af, bf[n], gacc[mm][n], 0,0,0);
        }
    }
    __syncthreads();   // done reading Xs; reuse it as transpose buffer

    #pragma unroll
    for (int mm=0; mm<3; ++mm) {
        #pragma unroll
        for (int r=0;r<4;r++) {
            const int oc = (3*wv+mm)*16 + kg*4 + r;
            const float ba = w1_b[oc], bb = w1_b[oc+192];
            #pragma unroll
            for (int n=0;n<4;n++) {
                const float a  = gacc[mm][n][r]   + ba;
                const float bv = gacc[mm+3][n][r] + bb;
                Xs[n*16+lx][oc] = __float2bfloat16(a * (1.f/(1.f+__expf(-bv))));
            }
        }
    }
    __syncthreads();

    __hip_bfloat16* gb = g + ((size_t)bimg*HWSZ + (size_t)y*192 + x0)*192;
    for (int idx = tid; idx < 64*24; idx += 256){
        int p = idx / 24, c8 = (idx - p*24)*8;
        *(uint4*)&gb[(size_t)p*192 + c8] = *(const uint4*)&Xs[p][c8];
    }
}

// ---------------------------------------------------------------------------
// K3: 3x3 conv via 9-tap shifted MFMA GEMM (unchanged from R2)
// ---------------------------------------------------------------------------
#define KC 32
__global__ __launch_bounds__(256)
void conv_mfma(const __hip_bfloat16* __restrict__ g,
               const __hip_bfloat16* __restrict__ wg,
               const float* __restrict__ w2_b, float* __restrict__ out)
{
    __shared__ __align__(16) __hip_bfloat16 gt[10*18*32];
    __shared__ __align__(16) __hip_bfloat16 wt[9*96*32];

    int bid = blockIdx.x;
    const int tX = bid % 12; bid /= 12;
    const int tY = bid % 24; bid /= 24;
    const int ob = bid & 1;  bid >>= 1;
    const int bimg = bid;
    const int tx0 = tX*16, ty0 = tY*8, oc0 = ob*96;

    const int tid  = threadIdx.x;
    const int lane = tid & 63;
    const int wv   = tid >> 6;
    const int wm   = wv >> 1;
    const int wn   = wv & 1;
    const int lx   = lane & 15;
    const int kg   = lane >> 4;

    f32x4 acc[3][4];
    #pragma unroll
    for (int m=0;m<3;m++)
        #pragma unroll
        for (int n=0;n<4;n++) acc[m][n] = (f32x4){0.f,0.f,0.f,0.f};

    const size_t gbase = (size_t)bimg*HWSZ;

    for (int c0 = 0; c0 < 192; c0 += KC) {
        for (int idx = tid; idx < 720; idx += 256) {
            int px = idx >> 2, part = idx & 3;
            int iy = px / 18, ix = px - iy*18;
            int gy = min(max(ty0 + iy - 1, 0), 191);
            int gx = min(max(tx0 + ix - 1, 0), 191);
            *(uint4*)&gt[(iy*18+ix)*32 + part*8] =
                *(const uint4*)&g[(gbase + (size_t)gy*192 + gx)*192 + c0 + part*8];
        }
        for (int idx = tid; idx < 3456; idx += 256) {
            int tap = idx / 384; int rr = idx - tap*384;
            int ocl = rr >> 2, part = rr & 3;
            *(uint4*)&wt[(tap*96+ocl)*32 + part*8] =
                *(const uint4*)&wg[(size_t)tap*36864 + (size_t)(oc0+ocl)*192 + c0 + part*8];
        }
        __syncthreads();

        #pragma unroll
        for (int ky=0; ky<3; ++ky) {
            #pragma unroll
            for (int kx=0; kx<3; ++kx) {
                const int tap = ky*3+kx;
                short8v a[3], b[4];
                #pragma unroll
                for (int m=0;m<3;m++)
                    a[m] = *(const short8v*)&wt[(tap*96 + wm*48 + m*16 + lx)*32 + kg*8];
                #pragma unroll
                for (int n=0;n<4;n++)
                    b[n] = *(const short8v*)&gt[((wn*4 + n + ky)*18 + lx + kx)*32 + kg*8];
                #pragma unroll
                for (int m=0;m<3;m++)
                    #pragma unroll
                    for (int n=0;n<4;n++)
                        acc[m][n] = __builtin_amdgcn_mfma_f32_16x16x32_bf16(
                                        a[m], b[n], acc[m][n], 0, 0, 0);
            }
        }
        __syncthreads();
    }

    #pragma unroll
    for (int m=0;m<3;m++) {
        const int ocb_ = oc0 + wm*48 + m*16 + kg*4;
        #pragma unroll
        for (int n=0;n<4;n++) {
            const int y = ty0 + wn*4 + n;
            const int x = tx0 + lx;
            #pragma unroll
            for (int r=0;r<4;r++) {
                const int oc = ocb_ + r;
                const size_t o = ((size_t)(bimg*192+oc))*HWSZ + (size_t)y*192 + x;
                float v = acc[m][n][r] + w2_b[oc];
                v = (v >= 0.f) ? v : 0.2f*v;
                out[o] += v;
            }
        }
    }
}

// ---------------------------------------------------------------------------
extern "C" void kernel_launch(void* const* d_in, const int* in_sizes, int n_in,
                              void* d_out, int out_size, void* d_ws, size_t ws_size,
                              hipStream_t stream)
{
    const float* x        = (const float*)d_in[0];
    const float* qkv_w    = (const float*)d_in[1];
    const float* qkv_b    = (const float*)d_in[2];
    const float* proj_w   = (const float*)d_in[3];
    const float* proj_b   = (const float*)d_in[4];
    const float* bias_tab = (const float*)d_in[5];
    const float* w1_w     = (const float*)d_in[6];
    const float* w1_b     = (const float*)d_in[7];
    const float* w2_w     = (const float*)d_in[8];
    const float* w2_b     = (const float*)d_in[9];
    float* out = (float*)d_out;

    __hip_bfloat16* g   = (__hip_bfloat16*)d_ws;                 // 113.2 MB
    char* wp = (char*)d_ws + (size_t)8*HWSZ*192*2;
    __hip_bfloat16* wg  = (__hip_bfloat16*)wp;
    __hip_bfloat16* wqp = (__hip_bfloat16*)(wp + (size_t)WG_N*2);
    __hip_bfloat16* pwp = (__hip_bfloat16*)(wp + (size_t)(WG_N+WQ_N)*2);
    __hip_bfloat16* w1b = (__hip_bfloat16*)(wp + (size_t)(WG_N+WQ_N+PW_N)*2);

    prep_weights<<<2208, 256, 0, stream>>>(w2_w, qkv_w, proj_w, w1_w, wg, wqp, pwp, w1b);
    attn_mfma<<<4608, 256, 0, stream>>>(x, wqp, qkv_b, pwp, proj_b, bias_tab, out);
    glu_mfma <<<4608, 256, 0, stream>>>(out, w1b, w1_b, g);
    conv_mfma<<<4608, 256, 0, stream>>>(g, wg, w2_b, out);
}